// Round 10
// baseline (306.388 us; speedup 1.0000x reference)
//
#include <hip/hip_runtime.h>
#include <hip/hip_bf16.h>

// GraphAE: pseudo == 0 => only W[0] of the 8 spline matrices matters.
// Linearization: mean(h[src])@W2_0 == mean(h[src]@W2_0) -> project before gather.
// Round 10: consumer-side fusion. Pipeline is 5 kernels:
//   prep (packs + x->bf16 + bucket hist) -> partition -> bucket_fill ->
//   fused_l1  [gather agg1 -> LDS -> L1 GEMM -> proj -> hwroot]
//   fused_dec [gather z    -> LDS -> dec1    -> dec2 -> out]
// agg1 and z never touch global; gather blocks co-schedule with MFMA blocks.
//
// Verified MFMA layouts (guide §3): A[m=lane&15][k=(lane>>4)*8+j],
// B[k=(lane>>4)*8+j][n=lane&15], D[row=(lane>>4)*4+r][col=lane&15].

#define THREADS 256

typedef __attribute__((ext_vector_type(8))) short bf16x8;   // 8 bf16 = 4 VGPRs
typedef __attribute__((ext_vector_type(4))) float f32x4;    // acc

__device__ __forceinline__ float bf2f(unsigned short u) {
    unsigned v = ((unsigned)u) << 16;
    return __builtin_bit_cast(float, v);
}
__device__ __forceinline__ unsigned short f2bf(float f) {
    __hip_bfloat16 h = __float2bfloat16(f);   // RNE
    return __builtin_bit_cast(unsigned short, h);
}
__device__ __forceinline__ void acc4(float* f, uint2 v) {
    f[0] += bf2f((unsigned short)v.x);
    f[1] += bf2f((unsigned short)(v.x >> 16));
    f[2] += bf2f((unsigned short)v.y);
    f[3] += bf2f((unsigned short)(v.y >> 16));
}

// Per-node gather: wave-uniform node; lane = slot(4) x c(16); tab pre-offset
// by c*4; rs = row stride in shorts. Returns feature sums r[0..3].
__device__ __forceinline__ void gather_node(
    const unsigned short* __restrict__ tab, int rs,
    const int* __restrict__ esrc, int s, int e, int slot, float* r)
{
    float a0[4] = {}, a1[4] = {}, a2[4] = {}, a3[4] = {};
    int j = s;
    for (; j + 16 <= e; j += 16) {
        int i0 = esrc[j + slot],      i1 = esrc[j + 4 + slot];
        int i2 = esrc[j + 8 + slot],  i3 = esrc[j + 12 + slot];
        uint2 v0 = *(const uint2*)(tab + (size_t)i0 * rs);
        uint2 v1 = *(const uint2*)(tab + (size_t)i1 * rs);
        uint2 v2 = *(const uint2*)(tab + (size_t)i2 * rs);
        uint2 v3 = *(const uint2*)(tab + (size_t)i3 * rs);
        acc4(a0, v0); acc4(a1, v1); acc4(a2, v2); acc4(a3, v3);
    }
    for (; j + 4 <= e; j += 4) {
        uint2 v0 = *(const uint2*)(tab + (size_t)esrc[j + slot] * rs);
        acc4(a0, v0);
    }
    if (slot < e - j) {
        uint2 v0 = *(const uint2*)(tab + (size_t)esrc[j + slot] * rs);
        acc4(a1, v0);
    }
#pragma unroll
    for (int k = 0; k < 4; ++k) {
        float v = (a0[k] + a1[k]) + (a2[k] + a3[k]);
        v += __shfl_xor(v, 16);
        v += __shfl_xor(v, 32);
        r[k] = v;
    }
}

// ---------------- weight pack ----------------
// Pack fp32 W (eff. K x NOUT) into MFMA B-frag layout bf16:
// dst[(((s*NB + j)*64 + lane)*8 + i] = W[s*32 + (lane>>4)*8 + i][j*16 + (lane&15)]
__device__ __forceinline__ void pack_one(unsigned short* dst,
                                         const float* W0, const float* W1,
                                         int NB, int ksplit, int colsplit,
                                         int ld0, int ld1, int t) {
    int i = t & 7, lane = (t >> 3) & 63, rest = t >> 9;
    int j = rest % NB, s = rest / NB;
    int k = s * 32 + ((lane >> 4) << 3) + i;
    int c = (j << 4) + (lane & 15);
    float v;
    if (c >= colsplit)    v = W1[(size_t)k * ld1 + (c - colsplit)];
    else if (k >= ksplit) v = W1[(size_t)(k - ksplit) * ld1 + c];
    else                  v = W0[(size_t)k * ld0 + c];
    dst[t] = f2bf(v);
}

#define BIG (1 << 30)

// prep: weight packs + x->bf16 (xb, N x 64) + bucket histogram (edge blocks)
__global__ void prep_kernel(const float* __restrict__ W1g, const float* __restrict__ root1,
                            const float* __restrict__ W2g, const float* __restrict__ root2,
                            const float* __restrict__ dw1, const float* __restrict__ dw2,
                            const float* __restrict__ x, const int* __restrict__ dstv,
                            int* __restrict__ bcnt,
                            unsigned short* __restrict__ Pb1,   // 128x256
                            unsigned short* __restrict__ Pb2,   // 256x128
                            unsigned short* __restrict__ Pd1,   // 64x256
                            unsigned short* __restrict__ Pd2,   // 256x64
                            unsigned short* __restrict__ xb,    // N x 64 bf16
                            int n, int E, int pb_pack) {
    if ((int)blockIdx.x >= pb_pack) {
        __shared__ int hist[256];
        int t = threadIdx.x;
        hist[t] = 0;
        __syncthreads();
        int e0 = ((int)blockIdx.x - pb_pack) * 4096;
#pragma unroll
        for (int i = 0; i < 16; ++i) {
            int e = e0 + t + i * 256;
            if (e < E) atomicAdd(&hist[dstv[e] >> 8], 1);
        }
        __syncthreads();
        int h = hist[t];
        if (h) atomicAdd(&bcnt[t], h);
        return;
    }
    int t = blockIdx.x * blockDim.x + threadIdx.x;
    if (t < 32768) {
        pack_one(Pb1, W1g, root1, 16, 64, BIG, 256, 256, t);
    } else if (t < 65536) {
        pack_one(Pb2, W2g, root2, 8, BIG, 64, 64, 64, t - 32768);
    } else if (t < 81920) {
        pack_one(Pd1, dw1, dw1, 16, BIG, BIG, 256, 256, t - 65536);
    } else if (t < 98304) {
        pack_one(Pd2, dw2, dw2, 4, BIG, BIG, 64, 64, t - 81920);
    } else if (t < 98304 + n * 16) {
        int u = t - 98304;
        int row = u >> 4, c4 = (u & 15) * 4;
        float4 v = *(const float4*)(x + (size_t)row * 64 + c4);
        unsigned lo = (unsigned)f2bf(v.x) | ((unsigned)f2bf(v.y) << 16);
        unsigned hi = (unsigned)f2bf(v.z) | ((unsigned)f2bf(v.w) << 16);
        uint2 o; o.x = lo; o.y = hi;
        *(uint2*)(xb + (size_t)row * 64 + c4) = o;
    }
}

// Pass A: partition edges into buckets of 256 consecutive dst nodes.
__global__ __launch_bounds__(256) void partition_edges(
    const int* __restrict__ src, const int* __restrict__ dst,
    const int* __restrict__ bcnt, int* __restrict__ bcur,
    int* __restrict__ epack, int E) {
    __shared__ int hist[256];
    __shared__ int base[256];
    __shared__ int lcur[256];
    __shared__ int bb[256];
    int t = threadIdx.x;
    hist[t] = 0;
    __syncthreads();
    int e0 = blockIdx.x * 4096;
    int myd[16], mys[16];
#pragma unroll
    for (int i = 0; i < 16; ++i) {
        int e = e0 + t + i * 256;
        int d = (e < E) ? dst[e] : -1;
        mys[i] = (e < E) ? src[e] : 0;
        myd[i] = d;
        if (d >= 0) atomicAdd(&hist[d >> 8], 1);
    }
    int cb = bcnt[t];
    bb[t] = cb;
    __syncthreads();
    for (int off = 1; off < 256; off <<= 1) {
        int xv = (t >= off) ? bb[t - off] : 0;
        __syncthreads();
        bb[t] += xv;
        __syncthreads();
    }
    int bbase_t = bb[t] - cb;
    int h = hist[t];
    if (h > 0) base[t] = bbase_t + atomicAdd(&bcur[t], h);
    lcur[t] = 0;
    __syncthreads();
#pragma unroll
    for (int i = 0; i < 16; ++i) {
        int d = myd[i];
        if (d >= 0) {
            int b = d >> 8;
            int p = atomicAdd(&lcur[b], 1);
            epack[base[b] + p] = ((d & 255) << 20) | mys[i];
        }
    }
}

// Pass B: per-bucket local histogram + scan (emits offs/invd), ordered esrc.
__global__ __launch_bounds__(256) void bucket_fill2(
    const int* __restrict__ epack, const int* __restrict__ bcnt,
    int* __restrict__ offs, float* __restrict__ invd,
    int* __restrict__ esrc, int N) {
    __shared__ int sb_[256];
    __shared__ int nh[256];
    __shared__ int loff[256];
    __shared__ int ncur[256];
    __shared__ int stage[8192];
    int b = blockIdx.x, t = threadIdx.x;
    int n0 = b << 8;
    int cntn = min(256, N - n0);
    int cb = bcnt[t];
    sb_[t] = cb;
    __syncthreads();
    for (int off = 1; off < 256; off <<= 1) {
        int xv = (t >= off) ? sb_[t - off] : 0;
        __syncthreads();
        sb_[t] += xv;
        __syncthreads();
    }
    int ebase = b ? sb_[b - 1] : 0;
    int ecount = sb_[b] - ebase;
    if (b == 0 && t == 0) offs[N] = sb_[255];
    nh[t] = 0;
    __syncthreads();
    for (int i = t; i < ecount; i += 256)
        atomicAdd(&nh[epack[ebase + i] >> 20], 1);
    __syncthreads();
    int v = nh[t];
    loff[t] = v;
    __syncthreads();
    for (int off = 1; off < 256; off <<= 1) {
        int xv = (t >= off) ? loff[t - off] : 0;
        __syncthreads();
        loff[t] += xv;
        __syncthreads();
    }
    int ex = loff[t] - v;
    loff[t] = ex;
    if (t < cntn) {
        offs[n0 + t] = ebase + ex;
        invd[n0 + t] = 1.0f / (float)max(v, 1);
    }
    ncur[t] = 0;
    __syncthreads();
    bool useLds = (ecount <= 8192);
    for (int i = t; i < ecount; i += 256) {
        int p = epack[ebase + i];
        int dl = p >> 20;
        int pos = atomicAdd(&ncur[dl], 1);
        int g = loff[dl] + pos;
        int sv = p & 0xFFFFF;
        if (useLds) stage[g] = sv;
        else        esrc[ebase + g] = sv;
    }
    __syncthreads();
    if (useLds)
        for (int i = t; i < ecount; i += 256) esrc[ebase + i] = stage[i];
}

// ---------------- fused layer-1: gather agg1 -> L1 GEMM -> projection ---------
// As[64][136]: cols 0:64 = gathered agg1, 64:128 = xb rows (root term).
// h tile lives in ht LDS; output hwroot (N x 128 bf16: hw | hroot).
__global__ __launch_bounds__(256) void fused_l1(
    const unsigned short* __restrict__ xb,
    const int* __restrict__ esrc, const int* __restrict__ offs,
    const float* __restrict__ invd,
    const unsigned short* __restrict__ Pb1, const float* __restrict__ b1,
    const unsigned short* __restrict__ Pb2,
    unsigned short* __restrict__ hwroot, int n)
{
    __shared__ unsigned short As[64][136];
    __shared__ unsigned short ht[64][264];
    const int m0 = blockIdx.x * 64;
    const int t = threadIdx.x;
    const int lane = t & 63, w = t >> 6;
    const int slot = lane >> 4, c = lane & 15;   // also quad/l16 for MFMA
    const int quad = slot, l16 = c;

    // gather phase: wave w handles rows w*16 .. w*16+15 (wave-uniform node)
#pragma unroll 1
    for (int i = 0; i < 16; ++i) {
        int row = w * 16 + i;
        int node = m0 + row;
        float r[4] = {0.f, 0.f, 0.f, 0.f};
        if (node < n)
            gather_node(xb + c * 4, 64, esrc, offs[node], offs[node + 1], slot, r);
        if (slot == 0) {
            float iv = (node < n) ? invd[node] : 0.f;
            unsigned lo = (unsigned)f2bf(r[0] * iv) | ((unsigned)f2bf(r[1] * iv) << 16);
            unsigned hi = (unsigned)f2bf(r[2] * iv) | ((unsigned)f2bf(r[3] * iv) << 16);
            uint2 o; o.x = lo; o.y = hi;
            *(uint2*)&As[row][c * 4] = o;
        }
    }
    // xb tile (root operand) into cols 64:128
    for (int i = t; i < 1024; i += 256) {
        int row = i >> 4, c4 = (i & 15) * 4;
        int node = m0 + row;
        uint2 v; v.x = 0u; v.y = 0u;
        if (node < n) v = *(const uint2*)(xb + (size_t)node * 64 + c4);
        *(uint2*)&As[row][64 + c4] = v;
    }
    __syncthreads();

    // stage 1: h = relu([agg|x] @ Pb1 + b1) -> ht
    {
        f32x4 acc[4][4] = {};
        for (int s = 0; s < 4; ++s) {
            bf16x8 a[4];
#pragma unroll
            for (int mb = 0; mb < 4; ++mb)
                a[mb] = *(const bf16x8*)&As[mb * 16 + l16][s * 32 + quad * 8];
#pragma unroll
            for (int jn = 0; jn < 4; ++jn) {
                int j = w * 4 + jn;
                bf16x8 b = *(const bf16x8*)(Pb1 + ((size_t)(s * 16 + j) * 64 + lane) * 8);
#pragma unroll
                for (int mb = 0; mb < 4; ++mb)
                    acc[mb][jn] = __builtin_amdgcn_mfma_f32_16x16x32_bf16(a[mb], b, acc[mb][jn], 0, 0, 0);
            }
        }
#pragma unroll
        for (int jn = 0; jn < 4; ++jn) {
            int col = (w * 4 + jn) * 16 + l16;
            float bv = b1[col];
#pragma unroll
            for (int mb = 0; mb < 4; ++mb)
#pragma unroll
                for (int r = 0; r < 4; ++r) {
                    int row = mb * 16 + quad * 4 + r;
                    ht[row][col] = f2bf(fmaxf(acc[mb][jn][r] + bv, 0.f));
                }
        }
    }
    __syncthreads();

    // stage 2: hwroot = ht @ Pb2  (128 cols out)
    {
        f32x4 acc[4][2] = {};
        for (int s = 0; s < 8; ++s) {
            bf16x8 a[4];
#pragma unroll
            for (int mb = 0; mb < 4; ++mb)
                a[mb] = *(const bf16x8*)&ht[mb * 16 + l16][s * 32 + quad * 8];
#pragma unroll
            for (int jn = 0; jn < 2; ++jn) {
                int j = w * 2 + jn;
                bf16x8 b = *(const bf16x8*)(Pb2 + ((size_t)(s * 8 + j) * 64 + lane) * 8);
#pragma unroll
                for (int mb = 0; mb < 4; ++mb)
                    acc[mb][jn] = __builtin_amdgcn_mfma_f32_16x16x32_bf16(a[mb], b, acc[mb][jn], 0, 0, 0);
            }
        }
#pragma unroll
        for (int jn = 0; jn < 2; ++jn) {
            int col = (w * 2 + jn) * 16 + l16;
#pragma unroll
            for (int mb = 0; mb < 4; ++mb)
#pragma unroll
                for (int r = 0; r < 4; ++r) {
                    int row = m0 + mb * 16 + quad * 4 + r;
                    if (row < n)
                        hwroot[(size_t)row * 128 + col] = f2bf(acc[mb][jn][r]);
                }
        }
    }
}

// ---------------- fused decoder: gather z -> dec1 -> dec2 -> out --------------
__global__ __launch_bounds__(256) void fused_dec(
    const unsigned short* __restrict__ hwroot,
    const int* __restrict__ esrc, const int* __restrict__ offs,
    const float* __restrict__ invd, const float* __restrict__ b2,
    const unsigned short* __restrict__ Pd1, const float* __restrict__ db1,
    const unsigned short* __restrict__ Pd2, const float* __restrict__ db2,
    float* __restrict__ out, int n)
{
    __shared__ unsigned short Az[64][72];
    __shared__ unsigned short ht[64][264];
    const int m0 = blockIdx.x * 64;
    const int t = threadIdx.x;
    const int lane = t & 63, w = t >> 6;
    const int slot = lane >> 4, c = lane & 15;
    const int quad = slot, l16 = c;

    // gather z phase
#pragma unroll 1
    for (int i = 0; i < 16; ++i) {
        int row = w * 16 + i;
        int node = m0 + row;
        float r[4] = {0.f, 0.f, 0.f, 0.f};
        if (node < n)
            gather_node(hwroot + c * 4, 128, esrc, offs[node], offs[node + 1], slot, r);
        if (slot == 0) {
            uint2 o; o.x = 0u; o.y = 0u;
            if (node < n) {
                float iv = invd[node];
                uint2 hr = *(const uint2*)(hwroot + (size_t)node * 128 + 64 + c * 4);
                float v0 = r[0] * iv + bf2f((unsigned short)hr.x) + b2[c * 4 + 0];
                float v1 = r[1] * iv + bf2f((unsigned short)(hr.x >> 16)) + b2[c * 4 + 1];
                float v2 = r[2] * iv + bf2f((unsigned short)hr.y) + b2[c * 4 + 2];
                float v3 = r[3] * iv + bf2f((unsigned short)(hr.y >> 16)) + b2[c * 4 + 3];
                o.x = (unsigned)f2bf(v0) | ((unsigned)f2bf(v1) << 16);
                o.y = (unsigned)f2bf(v2) | ((unsigned)f2bf(v3) << 16);
            }
            *(uint2*)&Az[row][c * 4] = o;
        }
    }
    __syncthreads();

    // stage 1: h2 = relu(z @ Pd1 + db1) -> ht   (K=64)
    {
        f32x4 acc[4][4] = {};
        for (int s = 0; s < 2; ++s) {
            bf16x8 a[4];
#pragma unroll
            for (int mb = 0; mb < 4; ++mb)
                a[mb] = *(const bf16x8*)&Az[mb * 16 + l16][s * 32 + quad * 8];
#pragma unroll
            for (int jn = 0; jn < 4; ++jn) {
                int j = w * 4 + jn;
                bf16x8 b = *(const bf16x8*)(Pd1 + ((size_t)(s * 16 + j) * 64 + lane) * 8);
#pragma unroll
                for (int mb = 0; mb < 4; ++mb)
                    acc[mb][jn] = __builtin_amdgcn_mfma_f32_16x16x32_bf16(a[mb], b, acc[mb][jn], 0, 0, 0);
            }
        }
#pragma unroll
        for (int jn = 0; jn < 4; ++jn) {
            int col = (w * 4 + jn) * 16 + l16;
            float bv = db1[col];
#pragma unroll
            for (int mb = 0; mb < 4; ++mb)
#pragma unroll
                for (int r = 0; r < 4; ++r) {
                    int row = mb * 16 + quad * 4 + r;
                    ht[row][col] = f2bf(fmaxf(acc[mb][jn][r] + bv, 0.f));
                }
        }
    }
    __syncthreads();

    // stage 2: out = ht @ Pd2 + db2  (64 cols, fp32)
    {
        f32x4 acc[4] = {};
        for (int s = 0; s < 8; ++s) {
            bf16x8 a[4];
#pragma unroll
            for (int mb = 0; mb < 4; ++mb)
                a[mb] = *(const bf16x8*)&ht[mb * 16 + l16][s * 32 + quad * 8];
            bf16x8 b = *(const bf16x8*)(Pd2 + ((size_t)(s * 4 + w) * 64 + lane) * 8);
#pragma unroll
            for (int mb = 0; mb < 4; ++mb)
                acc[mb] = __builtin_amdgcn_mfma_f32_16x16x32_bf16(a[mb], b, acc[mb], 0, 0, 0);
        }
        int col = w * 16 + l16;
        float bv = db2[col];
#pragma unroll
        for (int mb = 0; mb < 4; ++mb)
#pragma unroll
            for (int r = 0; r < 4; ++r) {
                int row = m0 + mb * 16 + quad * 4 + r;
                if (row < n)
                    out[(size_t)row * 64 + col] = acc[mb][r] + bv;
            }
    }
}

extern "C" void kernel_launch(void* const* d_in, const int* in_sizes, int n_in,
                              void* d_out, int out_size, void* d_ws, size_t ws_size,
                              hipStream_t stream) {
    const float* x      = (const float*)d_in[0];
    const int*   ei     = (const int*)d_in[1];
    const float* W1g    = (const float*)d_in[2];   // (8,64,256): [0] = first 16384
    const float* root1  = (const float*)d_in[3];
    const float* b1     = (const float*)d_in[4];
    const float* W2g    = (const float*)d_in[5];   // (8,256,64): [0] = first 16384
    const float* root2  = (const float*)d_in[6];
    const float* b2     = (const float*)d_in[7];
    const float* dw1    = (const float*)d_in[8];
    const float* db1    = (const float*)d_in[9];
    const float* dw2    = (const float*)d_in[10];
    const float* db2    = (const float*)d_in[11];
    float* out = (float*)d_out;

    const int N = in_sizes[0] / 64;
    const int E = in_sizes[1] / 2;
    const int Npad = N + 64;
    const int* srcv = ei;
    const int* dstv = ei + E;

    char* ws = (char*)d_ws;
    auto alloc = [&](size_t bytes) -> void* {
        void* p = (void*)ws;
        ws += (bytes + 255) & ~(size_t)255;
        return p;
    };
    int*   bcnt   = (int*)alloc(1024);               // per-bucket counts (256)
    int*   bcur   = (int*)alloc(1024);               // 0-based bucket cursors
    int*   offs   = (int*)alloc((size_t)(N + 1) * 4);
    float* invd   = (float*)alloc((size_t)N * 4);
    int*   esrc   = (int*)alloc((size_t)E * 4);
    int*   epack  = (int*)alloc((size_t)E * 4);
    unsigned short* Pb1 = (unsigned short*)alloc(32768 * 2);
    unsigned short* Pb2 = (unsigned short*)alloc(32768 * 2);
    unsigned short* Pd1 = (unsigned short*)alloc(16384 * 2);
    unsigned short* Pd2 = (unsigned short*)alloc(16384 * 2);
    unsigned short* xb     = (unsigned short*)alloc((size_t)Npad * 64 * 2);
    unsigned short* hwroot = (unsigned short*)alloc((size_t)Npad * 128 * 2);

    hipMemsetAsync(bcnt, 0, 2048, stream);           // bcnt + bcur (adjacent)

    int gb = (N + 63) / 64;
    int nbkt = (N + 255) / 256;
    int pa = (E + 4095) / 4096;
    int pb_pack = (98304 + N * 16 + THREADS - 1) / THREADS;

    // packs + x->bf16 + bucket histogram (one kernel, disjoint block ranges)
    prep_kernel<<<pb_pack + pa, THREADS, 0, stream>>>(
        W1g, root1, W2g, root2, dw1, dw2, x, dstv, bcnt,
        Pb1, Pb2, Pd1, Pd2, xb, N, E, pb_pack);
    // bucket-level CSR
    partition_edges<<<pa, 256, 0, stream>>>(srcv, dstv, bcnt, bcur, epack, E);
    bucket_fill2<<<nbkt, 256, 0, stream>>>(epack, bcnt, offs, invd, esrc, N);

    // fused layer 1: gather agg1 -> L1 GEMM -> projection -> hwroot
    fused_l1<<<gb, 256, 0, stream>>>(xb, esrc, offs, invd, Pb1, b1, Pb2, hwroot, N);
    // fused decoder: gather z -> dec1 -> dec2 -> out
    fused_dec<<<gb, 256, 0, stream>>>(hwroot, esrc, offs, invd, b2,
                                      Pd1, db1, Pd2, db2, out, N);
}

// Round 11
// 212.772 us; speedup vs baseline: 1.4400x; 1.4400x over previous
//
#include <hip/hip_runtime.h>
#include <hip/hip_bf16.h>

// GraphAE: pseudo == 0 => only W[0] of the 8 spline matrices matters.
// Linearization: mean(h[src])@W2_0 == mean(h[src]@W2_0) -> project before gather.
// Round 11 = round 9 structure (separate high-parallelism gather kernels;
// fusion of gather into GEMM kernels regressed 1.5x in round 10) + compact
// N x 64 gather tables (xb, agg1, hw, hroot, z): halves both gathers' working
// sets (12.8 -> 6.4 MB, ~L2-resident) and wastes no bytes per 128B fetch.
//
// Verified MFMA layouts (guide §3): A[m=lane&15][k=(lane>>4)*8+j],
// B[k=(lane>>4)*8+j][n=lane&15], D[row=(lane>>4)*4+r][col=lane&15].

#define THREADS 256

typedef __attribute__((ext_vector_type(8))) short bf16x8;   // 8 bf16 = 4 VGPRs
typedef __attribute__((ext_vector_type(4))) float f32x4;    // acc

__device__ __forceinline__ float bf2f(unsigned short u) {
    unsigned v = ((unsigned)u) << 16;
    return __builtin_bit_cast(float, v);
}
__device__ __forceinline__ unsigned short f2bf(float f) {
    __hip_bfloat16 h = __float2bfloat16(f);   // RNE
    return __builtin_bit_cast(unsigned short, h);
}
__device__ __forceinline__ void acc4(float* f, uint2 v) {
    f[0] += bf2f((unsigned short)v.x);
    f[1] += bf2f((unsigned short)(v.x >> 16));
    f[2] += bf2f((unsigned short)v.y);
    f[3] += bf2f((unsigned short)(v.y >> 16));
}

// ---------------- weight pack ----------------
// Pack fp32 W (eff. K x NOUT) into MFMA B-frag layout bf16:
// dst[(((s*NB + j)*64 + lane)*8 + i] = W[s*32 + (lane>>4)*8 + i][j*16 + (lane&15)]
__device__ __forceinline__ void pack_one(unsigned short* dst,
                                         const float* W0, const float* W1,
                                         int NB, int ksplit, int colsplit,
                                         int ld0, int ld1, int t) {
    int i = t & 7, lane = (t >> 3) & 63, rest = t >> 9;
    int j = rest % NB, s = rest / NB;
    int k = s * 32 + ((lane >> 4) << 3) + i;
    int c = (j << 4) + (lane & 15);
    float v;
    if (c >= colsplit)    v = W1[(size_t)k * ld1 + (c - colsplit)];
    else if (k >= ksplit) v = W1[(size_t)(k - ksplit) * ld1 + c];
    else                  v = W0[(size_t)k * ld0 + c];
    dst[t] = f2bf(v);
}

#define BIG (1 << 30)

// prep: weight packs + x->bf16 (xb, N x 64) + bucket histogram (edge blocks)
__global__ void prep_kernel(const float* __restrict__ W1g, const float* __restrict__ root1,
                            const float* __restrict__ W2g, const float* __restrict__ root2,
                            const float* __restrict__ dw1, const float* __restrict__ dw2,
                            const float* __restrict__ x, const int* __restrict__ dstv,
                            int* __restrict__ bcnt,
                            unsigned short* __restrict__ Pb1,   // 128x256
                            unsigned short* __restrict__ Pb2,   // 256x128
                            unsigned short* __restrict__ Pd1,   // 64x256
                            unsigned short* __restrict__ Pd2,   // 256x64
                            unsigned short* __restrict__ xb,    // N x 64 bf16
                            int n, int E, int pb_pack) {
    if ((int)blockIdx.x >= pb_pack) {
        __shared__ int hist[256];
        int t = threadIdx.x;
        hist[t] = 0;
        __syncthreads();
        int e0 = ((int)blockIdx.x - pb_pack) * 4096;
#pragma unroll
        for (int i = 0; i < 16; ++i) {
            int e = e0 + t + i * 256;
            if (e < E) atomicAdd(&hist[dstv[e] >> 8], 1);
        }
        __syncthreads();
        int h = hist[t];
        if (h) atomicAdd(&bcnt[t], h);
        return;
    }
    int t = blockIdx.x * blockDim.x + threadIdx.x;
    if (t < 32768) {
        pack_one(Pb1, W1g, root1, 16, 64, BIG, 256, 256, t);
    } else if (t < 65536) {
        pack_one(Pb2, W2g, root2, 8, BIG, 64, 64, 64, t - 32768);
    } else if (t < 81920) {
        pack_one(Pd1, dw1, dw1, 16, BIG, BIG, 256, 256, t - 65536);
    } else if (t < 98304) {
        pack_one(Pd2, dw2, dw2, 4, BIG, BIG, 64, 64, t - 81920);
    } else if (t < 98304 + n * 16) {
        int u = t - 98304;
        int row = u >> 4, c4 = (u & 15) * 4;
        float4 v = *(const float4*)(x + (size_t)row * 64 + c4);
        unsigned lo = (unsigned)f2bf(v.x) | ((unsigned)f2bf(v.y) << 16);
        unsigned hi = (unsigned)f2bf(v.z) | ((unsigned)f2bf(v.w) << 16);
        uint2 o; o.x = lo; o.y = hi;
        *(uint2*)(xb + (size_t)row * 64 + c4) = o;
    }
}

// Pass A: partition edges into buckets of 256 consecutive dst nodes.
__global__ __launch_bounds__(256) void partition_edges(
    const int* __restrict__ src, const int* __restrict__ dst,
    const int* __restrict__ bcnt, int* __restrict__ bcur,
    int* __restrict__ epack, int E) {
    __shared__ int hist[256];
    __shared__ int base[256];
    __shared__ int lcur[256];
    __shared__ int bb[256];
    int t = threadIdx.x;
    hist[t] = 0;
    __syncthreads();
    int e0 = blockIdx.x * 4096;
    int myd[16], mys[16];
#pragma unroll
    for (int i = 0; i < 16; ++i) {
        int e = e0 + t + i * 256;
        int d = (e < E) ? dst[e] : -1;
        mys[i] = (e < E) ? src[e] : 0;
        myd[i] = d;
        if (d >= 0) atomicAdd(&hist[d >> 8], 1);
    }
    int cb = bcnt[t];
    bb[t] = cb;
    __syncthreads();
    for (int off = 1; off < 256; off <<= 1) {
        int xv = (t >= off) ? bb[t - off] : 0;
        __syncthreads();
        bb[t] += xv;
        __syncthreads();
    }
    int bbase_t = bb[t] - cb;
    int h = hist[t];
    if (h > 0) base[t] = bbase_t + atomicAdd(&bcur[t], h);
    lcur[t] = 0;
    __syncthreads();
#pragma unroll
    for (int i = 0; i < 16; ++i) {
        int d = myd[i];
        if (d >= 0) {
            int b = d >> 8;
            int p = atomicAdd(&lcur[b], 1);
            epack[base[b] + p] = ((d & 255) << 20) | mys[i];
        }
    }
}

// Pass B: per-bucket local histogram + scan (emits offs/invd), ordered esrc.
__global__ __launch_bounds__(256) void bucket_fill2(
    const int* __restrict__ epack, const int* __restrict__ bcnt,
    int* __restrict__ offs, float* __restrict__ invd,
    int* __restrict__ esrc, int N) {
    __shared__ int sb_[256];
    __shared__ int nh[256];
    __shared__ int loff[256];
    __shared__ int ncur[256];
    __shared__ int stage[8192];
    int b = blockIdx.x, t = threadIdx.x;
    int n0 = b << 8;
    int cntn = min(256, N - n0);
    int cb = bcnt[t];
    sb_[t] = cb;
    __syncthreads();
    for (int off = 1; off < 256; off <<= 1) {
        int xv = (t >= off) ? sb_[t - off] : 0;
        __syncthreads();
        sb_[t] += xv;
        __syncthreads();
    }
    int ebase = b ? sb_[b - 1] : 0;
    int ecount = sb_[b] - ebase;
    if (b == 0 && t == 0) offs[N] = sb_[255];
    nh[t] = 0;
    __syncthreads();
    for (int i = t; i < ecount; i += 256)
        atomicAdd(&nh[epack[ebase + i] >> 20], 1);
    __syncthreads();
    int v = nh[t];
    loff[t] = v;
    __syncthreads();
    for (int off = 1; off < 256; off <<= 1) {
        int xv = (t >= off) ? loff[t - off] : 0;
        __syncthreads();
        loff[t] += xv;
        __syncthreads();
    }
    int ex = loff[t] - v;
    loff[t] = ex;
    if (t < cntn) {
        offs[n0 + t] = ebase + ex;
        invd[n0 + t] = 1.0f / (float)max(v, 1);
    }
    ncur[t] = 0;
    __syncthreads();
    bool useLds = (ecount <= 8192);
    for (int i = t; i < ecount; i += 256) {
        int p = epack[ebase + i];
        int dl = p >> 20;
        int pos = atomicAdd(&ncur[dl], 1);
        int g = loff[dl] + pos;
        int sv = p & 0xFFFFF;
        if (useLds) stage[g] = sv;
        else        esrc[ebase + g] = sv;
    }
    __syncthreads();
    if (useLds)
        for (int i = t; i < ecount; i += 256) esrc[ebase + i] = stage[i];
}

// ---------------- gathers: 8B/lane, 4 edges per wave-instr, 16-edge unroll ----
// lane = slot(4) x c(16); lane loads features [c*4, c*4+4) of edge (j+slot).
// agg1 = mean(xb[src]) -> agg1 table (both N x 64, 128B rows)
__global__ void agg_x4(const unsigned short* __restrict__ xb,
                       unsigned short* __restrict__ agg1,
                       const int* __restrict__ esrc, const int* __restrict__ offs,
                       const float* __restrict__ invd, int n) {
    int node = blockIdx.x * 4 + (threadIdx.x >> 6);
    if (node >= n) return;
    int l = threadIdx.x & 63;
    int slot = l >> 4, c = l & 15;
    const unsigned short* tb = xb + c * 4;
    int s = offs[node], e = offs[node + 1];
    float a0[4] = {}, a1[4] = {}, a2[4] = {}, a3[4] = {};
    int j = s;
    for (; j + 16 <= e; j += 16) {
        int i0 = esrc[j + slot],      i1 = esrc[j + 4 + slot];
        int i2 = esrc[j + 8 + slot],  i3 = esrc[j + 12 + slot];
        uint2 v0 = *(const uint2*)(tb + (size_t)i0 * 64);
        uint2 v1 = *(const uint2*)(tb + (size_t)i1 * 64);
        uint2 v2 = *(const uint2*)(tb + (size_t)i2 * 64);
        uint2 v3 = *(const uint2*)(tb + (size_t)i3 * 64);
        acc4(a0, v0); acc4(a1, v1); acc4(a2, v2); acc4(a3, v3);
    }
    for (; j + 4 <= e; j += 4) {
        uint2 v0 = *(const uint2*)(tb + (size_t)esrc[j + slot] * 64);
        acc4(a0, v0);
    }
    if (slot < e - j) {
        uint2 v0 = *(const uint2*)(tb + (size_t)esrc[j + slot] * 64);
        acc4(a1, v0);
    }
    float r[4];
#pragma unroll
    for (int k = 0; k < 4; ++k) {
        r[k] = (a0[k] + a1[k]) + (a2[k] + a3[k]);
        r[k] += __shfl_xor(r[k], 16);
        r[k] += __shfl_xor(r[k], 32);
    }
    if (slot == 0) {
        float iv = invd[node];
        unsigned lo = (unsigned)f2bf(r[0] * iv) | ((unsigned)f2bf(r[1] * iv) << 16);
        unsigned hi = (unsigned)f2bf(r[2] * iv) | ((unsigned)f2bf(r[3] * iv) << 16);
        uint2 o; o.x = lo; o.y = hi;
        *(uint2*)(agg1 + (size_t)node * 64 + c * 4) = o;
    }
}

// z = mean(hw[src]) + hroot + b2 ; hw/hroot/z all N x 64 bf16
__global__ void agg_z4(const unsigned short* __restrict__ hw,
                       const unsigned short* __restrict__ hroot,
                       const int* __restrict__ esrc, const int* __restrict__ offs,
                       const float* __restrict__ invd, const float* __restrict__ b2,
                       unsigned short* __restrict__ z, int n) {
    int node = blockIdx.x * 4 + (threadIdx.x >> 6);
    if (node >= n) return;
    int l = threadIdx.x & 63;
    int slot = l >> 4, c = l & 15;
    const unsigned short* tb = hw + c * 4;
    int s = offs[node], e = offs[node + 1];
    float a0[4] = {}, a1[4] = {}, a2[4] = {}, a3[4] = {};
    int j = s;
    for (; j + 16 <= e; j += 16) {
        int i0 = esrc[j + slot],      i1 = esrc[j + 4 + slot];
        int i2 = esrc[j + 8 + slot],  i3 = esrc[j + 12 + slot];
        uint2 v0 = *(const uint2*)(tb + (size_t)i0 * 64);
        uint2 v1 = *(const uint2*)(tb + (size_t)i1 * 64);
        uint2 v2 = *(const uint2*)(tb + (size_t)i2 * 64);
        uint2 v3 = *(const uint2*)(tb + (size_t)i3 * 64);
        acc4(a0, v0); acc4(a1, v1); acc4(a2, v2); acc4(a3, v3);
    }
    for (; j + 4 <= e; j += 4) {
        uint2 v0 = *(const uint2*)(tb + (size_t)esrc[j + slot] * 64);
        acc4(a0, v0);
    }
    if (slot < e - j) {
        uint2 v0 = *(const uint2*)(tb + (size_t)esrc[j + slot] * 64);
        acc4(a1, v0);
    }
    float r[4];
#pragma unroll
    for (int k = 0; k < 4; ++k) {
        r[k] = (a0[k] + a1[k]) + (a2[k] + a3[k]);
        r[k] += __shfl_xor(r[k], 16);
        r[k] += __shfl_xor(r[k], 32);
    }
    if (slot == 0) {
        float iv = invd[node];
        uint2 hr = *(const uint2*)(hroot + (size_t)node * 64 + c * 4);
        float v0 = r[0] * iv + bf2f((unsigned short)hr.x) + b2[c * 4 + 0];
        float v1 = r[1] * iv + bf2f((unsigned short)(hr.x >> 16)) + b2[c * 4 + 1];
        float v2 = r[2] * iv + bf2f((unsigned short)hr.y) + b2[c * 4 + 2];
        float v3 = r[3] * iv + bf2f((unsigned short)(hr.y >> 16)) + b2[c * 4 + 3];
        unsigned lo = (unsigned)f2bf(v0) | ((unsigned)f2bf(v1) << 16);
        unsigned hi = (unsigned)f2bf(v2) | ((unsigned)f2bf(v3) << 16);
        uint2 o; o.x = lo; o.y = hi;
        *(uint2*)(z + (size_t)node * 64 + c * 4) = o;
    }
}

// ---------------- fused double-GEMM ----------------
// Stage 1: T = relu(A @ Wp1 + bias1); A is K1 cols from one or two N x 64
// tables (SPLITA: k<64 from A0, k>=64 from A1). T: 64 x 256 tile in LDS.
// Stage 2: C = T @ Wp2 (+ bias2); NOUT2 = NBW2*64. OUTFP32: fp32 C with bias2;
// else bf16 split across out0 (cols 0:64) / out1 (cols 64:128).
template <int K1, int NBW2, bool SPLITA, bool OUTFP32>
__global__ __launch_bounds__(256) void gemm_fused(
    const unsigned short* __restrict__ A0, const unsigned short* __restrict__ A1,
    const unsigned short* __restrict__ Bp1, const float* __restrict__ bias1,
    const unsigned short* __restrict__ Bp2, const float* __restrict__ bias2,
    void* __restrict__ out0, unsigned short* __restrict__ out1, int n)
{
    constexpr int KS1 = K1 / 32;
    constexpr int NB2 = NBW2 * 4;
    __shared__ unsigned short ht[64][264];

    const int m0 = blockIdx.x * 64;
    const int lane = threadIdx.x & 63;
    const int w = threadIdx.x >> 6;
    const int quad = lane >> 4;
    const int l16 = lane & 15;

    // ---- stage 1 ----
    {
        f32x4 acc[4][4] = {};
        for (int s = 0; s < KS1; ++s) {
            const unsigned short* tab;
            int ks;
            if (SPLITA && s >= KS1 / 2) { tab = A1; ks = s - KS1 / 2; }
            else                        { tab = A0; ks = s; }
            const unsigned short* Arow = tab + (size_t)(m0 + l16) * 64 + ks * 32 + quad * 8;
            bf16x8 a[4];
#pragma unroll
            for (int mb = 0; mb < 4; ++mb)
                a[mb] = *(const bf16x8*)(Arow + (size_t)mb * 16 * 64);
#pragma unroll
            for (int jn = 0; jn < 4; ++jn) {
                int j = w * 4 + jn;
                bf16x8 b = *(const bf16x8*)(Bp1 + ((size_t)(s * 16 + j) * 64 + lane) * 8);
#pragma unroll
                for (int mb = 0; mb < 4; ++mb)
                    acc[mb][jn] = __builtin_amdgcn_mfma_f32_16x16x32_bf16(a[mb], b, acc[mb][jn], 0, 0, 0);
            }
        }
#pragma unroll
        for (int jn = 0; jn < 4; ++jn) {
            int col = (w * 4 + jn) * 16 + l16;
            float bv = bias1[col];
#pragma unroll
            for (int mb = 0; mb < 4; ++mb)
#pragma unroll
                for (int r = 0; r < 4; ++r) {
                    int row = mb * 16 + quad * 4 + r;
                    ht[row][col] = f2bf(fmaxf(acc[mb][jn][r] + bv, 0.f));
                }
        }
    }
    __syncthreads();

    // ---- stage 2 ----
    {
        f32x4 acc[4][NBW2] = {};
        for (int s = 0; s < 8; ++s) {
            bf16x8 a[4];
#pragma unroll
            for (int mb = 0; mb < 4; ++mb)
                a[mb] = *(const bf16x8*)&ht[mb * 16 + l16][s * 32 + quad * 8];
#pragma unroll
            for (int jn = 0; jn < NBW2; ++jn) {
                int j = w * NBW2 + jn;
                bf16x8 b = *(const bf16x8*)(Bp2 + ((size_t)(s * NB2 + j) * 64 + lane) * 8);
#pragma unroll
                for (int mb = 0; mb < 4; ++mb)
                    acc[mb][jn] = __builtin_amdgcn_mfma_f32_16x16x32_bf16(a[mb], b, acc[mb][jn], 0, 0, 0);
            }
        }
#pragma unroll
        for (int jn = 0; jn < NBW2; ++jn) {
            int col = (w * NBW2 + jn) * 16 + l16;
            float bv = (OUTFP32 && bias2) ? bias2[col] : 0.f;
#pragma unroll
            for (int mb = 0; mb < 4; ++mb)
#pragma unroll
                for (int r = 0; r < 4; ++r) {
                    int row = m0 + mb * 16 + quad * 4 + r;
                    if (row < n) {
                        float v = acc[mb][jn][r] + bv;
                        if (OUTFP32) {
                            ((float*)out0)[(size_t)row * 64 + col] = v;
                        } else if (col < 64) {
                            ((unsigned short*)out0)[(size_t)row * 64 + col] = f2bf(v);
                        } else {
                            out1[(size_t)row * 64 + (col - 64)] = f2bf(v);
                        }
                    }
                }
        }
    }
}

extern "C" void kernel_launch(void* const* d_in, const int* in_sizes, int n_in,
                              void* d_out, int out_size, void* d_ws, size_t ws_size,
                              hipStream_t stream) {
    const float* x      = (const float*)d_in[0];
    const int*   ei     = (const int*)d_in[1];
    const float* W1g    = (const float*)d_in[2];   // (8,64,256): [0] = first 16384
    const float* root1  = (const float*)d_in[3];
    const float* b1     = (const float*)d_in[4];
    const float* W2g    = (const float*)d_in[5];   // (8,256,64): [0] = first 16384
    const float* root2  = (const float*)d_in[6];
    const float* b2     = (const float*)d_in[7];
    const float* dw1    = (const float*)d_in[8];
    const float* db1    = (const float*)d_in[9];
    const float* dw2    = (const float*)d_in[10];
    const float* db2    = (const float*)d_in[11];
    float* out = (float*)d_out;

    const int N = in_sizes[0] / 64;
    const int E = in_sizes[1] / 2;
    const int Npad = N + 64;
    const int* srcv = ei;
    const int* dstv = ei + E;

    char* ws = (char*)d_ws;
    auto alloc = [&](size_t bytes) -> void* {
        void* p = (void*)ws;
        ws += (bytes + 255) & ~(size_t)255;
        return p;
    };
    int*   bcnt   = (int*)alloc(1024);               // per-bucket counts (256)
    int*   bcur   = (int*)alloc(1024);               // 0-based bucket cursors
    int*   offs   = (int*)alloc((size_t)(N + 1) * 4);
    float* invd   = (float*)alloc((size_t)N * 4);
    int*   esrc   = (int*)alloc((size_t)E * 4);
    int*   epack  = (int*)alloc((size_t)E * 4);
    unsigned short* Pb1 = (unsigned short*)alloc(32768 * 2);
    unsigned short* Pb2 = (unsigned short*)alloc(32768 * 2);
    unsigned short* Pd1 = (unsigned short*)alloc(16384 * 2);
    unsigned short* Pd2 = (unsigned short*)alloc(16384 * 2);
    unsigned short* xb    = (unsigned short*)alloc((size_t)Npad * 64 * 2);
    unsigned short* agg1  = (unsigned short*)alloc((size_t)Npad * 64 * 2);
    unsigned short* hw    = (unsigned short*)alloc((size_t)Npad * 64 * 2);
    unsigned short* hroot = (unsigned short*)alloc((size_t)Npad * 64 * 2);
    unsigned short* z     = (unsigned short*)alloc((size_t)Npad * 64 * 2);

    hipMemsetAsync(bcnt, 0, 2048, stream);           // bcnt + bcur (adjacent)

    int gb = (N + 63) / 64;
    int nbkt = (N + 255) / 256;
    int pa = (E + 4095) / 4096;
    int pb_pack = (98304 + N * 16 + THREADS - 1) / THREADS;

    // packs + x->bf16 + bucket histogram (one kernel, disjoint block ranges)
    prep_kernel<<<pb_pack + pa, THREADS, 0, stream>>>(
        W1g, root1, W2g, root2, dw1, dw2, x, dstv, bcnt,
        Pb1, Pb2, Pd1, Pd2, xb, N, E, pb_pack);
    // bucket-level CSR
    partition_edges<<<pa, 256, 0, stream>>>(srcv, dstv, bcnt, bcur, epack, E);
    bucket_fill2<<<nbkt, 256, 0, stream>>>(epack, bcnt, offs, invd, esrc, N);

    // layer 1: gather agg1, fused [L1 GEMM -> L2 projection] -> hw | hroot
    agg_x4<<<(N + 3) / 4, THREADS, 0, stream>>>(xb, agg1, esrc, offs, invd, N);
    gemm_fused<128, 2, true, false><<<gb, 256, 0, stream>>>(
        agg1, xb, Pb1, b1, Pb2, nullptr, hw, hroot, N);
    // layer 2 gather + epilogue -> z
    agg_z4<<<(N + 3) / 4, THREADS, 0, stream>>>(hw, hroot, esrc, offs, invd, b2, z, N);
    // fused decoder [dec1 -> dec2] -> out
    gemm_fused<64, 1, false, true><<<gb, 256, 0, stream>>>(
        z, nullptr, Pd1, db1, Pd2, db2, out, nullptr, N);
}